// Round 16
// baseline (132.931 us; speedup 1.0000x reference)
//
#include <hip/hip_runtime.h>

#define N_FEAT   128
#define N_GRAPHS 2048
#define BN_EPS   1e-5f
#define LDA      136   // padded LDS row length (bf16 elems)
#define FHLD     132   // padded float row length for pool staging
#define EPB      4096  // edges per partition block (nb2 = ceil(E/EPB) <= 256 required)

typedef __attribute__((ext_vector_type(8))) short  bf16x8;
typedef __attribute__((ext_vector_type(4))) float  f32x4;

__device__ __forceinline__ unsigned short f2bf(float f) {
    union { float f; unsigned int u; } c; c.f = f;
    unsigned int r = c.u + 0x7fffu + ((c.u >> 16) & 1u);   // RNE
    return (unsigned short)(r >> 16);
}
__device__ __forceinline__ float bf2f(unsigned short h) {
    union { unsigned int u; float f; } c; c.u = ((unsigned int)h) << 16;
    return c.f;
}

// add 8 packed bf16 (int4) into acc[8]
__device__ __forceinline__ void acc8(float* a, int4 u) {
    unsigned int w[4] = {(unsigned int)u.x, (unsigned int)u.y,
                         (unsigned int)u.z, (unsigned int)u.w};
    #pragma unroll
    for (int k = 0; k < 4; ++k) {
        a[2 * k]     += __uint_as_float(w[k] << 16);
        a[2 * k + 1] += __uint_as_float(w[k] & 0xffff0000u);
    }
}

// -------- fused prep: x->bf16 | W transpose->bf16 | graph counts | bhist ----
__global__ __launch_bounds__(256) void k_prep(const float* __restrict__ x,
                                              unsigned short* __restrict__ xb,
                                              int n8, int nbx,
                                              const float* __restrict__ W1,
                                              const float* __restrict__ W2,
                                              unsigned short* __restrict__ Wt1,
                                              unsigned short* __restrict__ Wt2,
                                              const int* __restrict__ batch,
                                              int* __restrict__ cnt, int n_nodes,
                                              int nbg,
                                              const int* __restrict__ dst,
                                              int* __restrict__ bcnt,
                                              int* __restrict__ btot,
                                              int n_edges, int nb2)
{
    int b = blockIdx.x, t = threadIdx.x;
    if (b < nbx) {
        int i = b * 256 + t;
        if (i >= n8) return;
        float4 a = ((const float4*)x)[i * 2];
        float4 c = ((const float4*)x)[i * 2 + 1];
        ushort4 u0, u1;
        u0.x = f2bf(a.x); u0.y = f2bf(a.y); u0.z = f2bf(a.z); u0.w = f2bf(a.w);
        u1.x = f2bf(c.x); u1.y = f2bf(c.y); u1.z = f2bf(c.z); u1.w = f2bf(c.w);
        ((ushort4*)xb)[i * 2]     = u0;
        ((ushort4*)xb)[i * 2 + 1] = u1;
    } else if (b < nbx + 128) {
        int i = (b - nbx) * 256 + t;   // 0..32767
        int which = i >> 14;
        int k = (i >> 7) & 127;
        int c = i & 127;
        const float* W = which ? W2 : W1;
        unsigned short* O = which ? Wt2 : Wt1;
        O[c * 128 + k] = f2bf(W[k * 128 + c]);
    } else if (b < nbx + 128 + nbg) {
        int i = (b - nbx - 128) * 256 + t;
        if (i < n_nodes) atomicAdd(&cnt[batch[i]], 1);
    } else {
        // bhist section: per-(block,bucket) histogram of dst
        __shared__ int lc[256];
        int blk = b - nbx - 128 - nbg;   // 0..nb2-1
        lc[t] = 0;
        __syncthreads();
        int base = blk * EPB;
        for (int i = t; i < EPB; i += 256) {
            int e = base + i;
            if (e < n_edges) atomicAdd(&lc[dst[e] >> 8], 1);
        }
        __syncthreads();
        bcnt[t * nb2 + blk] = lc[t];
        if (lc[t]) atomicAdd(&btot[t], lc[t]);
    }
}

// ---------------- CSR scan in ONE kernel ------------------------------------
__global__ __launch_bounds__(256) void k_bscan3(const int* __restrict__ bcnt,
                                                const int* __restrict__ btot,
                                                int* __restrict__ boff2, int nb2)
{
    __shared__ int s[256];
    int t = threadIdx.x, b = blockIdx.x;
    s[t] = (t < b) ? btot[t] : 0;
    __syncthreads();
    for (int o = 128; o > 0; o >>= 1) {
        if (t < o) s[t] += s[t + o];
        __syncthreads();
    }
    int base = s[0];
    __syncthreads();
    int c = (t < nb2) ? bcnt[b * nb2 + t] : 0;
    s[t] = c;
    __syncthreads();
    for (int o = 1; o < 256; o <<= 1) {
        int u = (t >= o) ? s[t - o] : 0;
        __syncthreads();
        s[t] += u;
        __syncthreads();
    }
    if (t < nb2) boff2[b * nb2 + t] = base + s[t] - c;
}

// ---------------- CSR sort stage 2: partition edges by bucket ----------------
__global__ __launch_bounds__(256) void k_part(const int* __restrict__ src,
                                              const int* __restrict__ dst,
                                              const int* __restrict__ boff2,
                                              unsigned* __restrict__ epart,
                                              int n_edges, int nb2)
{
    __shared__ int lc[256];
    __shared__ int lofs[256];
    __shared__ unsigned buf[EPB];
    int t = threadIdx.x, blk = blockIdx.x;
    int base = blk * EPB;
    lc[t] = 0;
    __syncthreads();
    for (int i = t; i < EPB; i += 256) {
        int e = base + i;
        if (e < n_edges) atomicAdd(&lc[dst[e] >> 8], 1);
    }
    __syncthreads();
    int v = lc[t];
    lofs[t] = v;
    __syncthreads();
    for (int o = 1; o < 256; o <<= 1) {
        int u = (t >= o) ? lofs[t - o] : 0;
        __syncthreads();
        lofs[t] += u;
        __syncthreads();
    }
    int excl = lofs[t] - v;
    __syncthreads();
    lofs[t] = excl;
    lc[t] = 0;
    __syncthreads();
    for (int i = t; i < EPB; i += 256) {
        int e = base + i;
        if (e < n_edges) {
            int d = dst[e];
            int b = d >> 8;
            unsigned pack = ((unsigned)d << 16) | (unsigned)src[e];
            int r = atomicAdd(&lc[b], 1);
            buf[lofs[b] + r] = pack;
        }
    }
    __syncthreads();
    int total = min(EPB, n_edges - base);
    for (int i = t; i < total; i += 256) {
        unsigned pack = buf[i];
        int b = pack >> 24;              // dst>>8
        int gpos = boff2[b * nb2 + blk] + (i - lofs[b]);
        epart[gpos] = pack;
    }
}

// ---------------- CSR sort stage 3: per-bucket fill (writes row_start too) --
__global__ __launch_bounds__(256) void k_bfill(const unsigned* __restrict__ epart,
                                               const int* __restrict__ boff2,
                                               int* __restrict__ row_start,
                                               unsigned short* __restrict__ csr,
                                               int n_nodes, int nb2, int nbkt)
{
    __shared__ int cur[256];
    __shared__ int sc2[256];
    __shared__ unsigned short seg[8192];
    int t = threadIdx.x, b = blockIdx.x;
    int node0 = b * 256;
    int nodes = min(256, n_nodes - node0);
    int ebeg = boff2[(size_t)b * nb2];
    int eend = (b + 1 < nbkt) ? boff2[(size_t)(b + 1) * nb2] : boff2[(size_t)nbkt * nb2];

    cur[t] = 0;
    __syncthreads();
    for (int i = ebeg + t; i < eend; i += 256)
        atomicAdd(&cur[(epart[i] >> 16) - node0], 1);
    __syncthreads();
    int v = cur[t];
    sc2[t] = v;
    __syncthreads();
    for (int o = 1; o < 256; o <<= 1) {
        int u = (t >= o) ? sc2[t - o] : 0;
        __syncthreads();
        sc2[t] += u;
        __syncthreads();
    }
    int excl = sc2[t] - v;
    if (t < nodes) row_start[node0 + t] = ebeg + excl;
    if (b == nbkt - 1 && t == 0) row_start[n_nodes] = eend;
    __syncthreads();
    cur[t] = excl;
    __syncthreads();
    for (int i = ebeg + t; i < eend; i += 256) {
        unsigned pack = epart[i];
        int idx = (pack >> 16) - node0;
        int slot = atomicAdd(&cur[idx], 1);
        seg[slot] = (unsigned short)(pack & 0xffffu);
    }
    __syncthreads();
    int seglen = eend - ebeg;
    for (int i = t; i < seglen; i += 256) csr[ebeg + i] = seg[i];
}

// ---------------- pull aggregation (bf16 neighbors + bf16 self) -> bf16 A ---
__global__ __launch_bounds__(256) void k_gather(const unsigned short* __restrict__ xb,
                                                const unsigned short* __restrict__ csr,
                                                const int* __restrict__ row_start,
                                                unsigned short* __restrict__ A,
                                                int n_nodes)
{
    int node = blockIdx.x * 4 + (threadIdx.x >> 6);
    if (node >= n_nodes) return;
    int l = threadIdx.x & 63;
    int q = l >> 4;          // quarter id: edge stream offset
    int lq = l & 15;         // feature group lq*8 .. lq*8+7
    const int4* xb4 = (const int4*)xb;
    int beg = row_start[node], end = row_start[node + 1];
    float a[8];
    #pragma unroll
    for (int i = 0; i < 8; ++i) a[i] = 0.f;

    int j = beg + q;
    for (; j + 12 < end; j += 16) {        // 16 edges in flight per wave
        int s0 = csr[j], s1 = csr[j + 4], s2 = csr[j + 8], s3 = csr[j + 12];
        int4 u0 = xb4[(size_t)s0 * 16 + lq];
        int4 u1 = xb4[(size_t)s1 * 16 + lq];
        int4 u2 = xb4[(size_t)s2 * 16 + lq];
        int4 u3 = xb4[(size_t)s3 * 16 + lq];
        acc8(a, u0);
        acc8(a, u1);
        acc8(a, u2);
        acc8(a, u3);
    }
    for (; j < end; j += 4) {
        int4 u = xb4[(size_t)csr[j] * 16 + lq];
        acc8(a, u);
    }
    #pragma unroll
    for (int i = 0; i < 8; ++i) {
        a[i] += __shfl_xor(a[i], 16);
        a[i] += __shfl_xor(a[i], 32);
    }
    if (q == 0) {
        int4 uself = xb4[(size_t)node * 16 + lq];
        acc8(a, uself);
        unsigned int hw[4];
        #pragma unroll
        for (int i = 0; i < 4; ++i) {
            unsigned short h0 = f2bf(a[2 * i]);
            unsigned short h1 = f2bf(a[2 * i + 1]);
            hw[i] = (unsigned int)h0 | ((unsigned int)h1 << 16);
        }
        *(int4*)(A + (size_t)node * 128 + lq * 8) = make_int4(hw[0], hw[1], hw[2], hw[3]);
    }
}

// --- fused MLP1 via MFMA + BN stats (direct atomics) + segmented pool -------
__global__ __launch_bounds__(256) void k_mlp1_mfma(const unsigned short* __restrict__ A,
                                                   const unsigned short* __restrict__ Wt1,
                                                   const float* __restrict__ b1,
                                                   const unsigned short* __restrict__ Wt2,
                                                   const float* __restrict__ b2,
                                                   const int* __restrict__ batch,
                                                   float* __restrict__ g_raw,
                                                   float* __restrict__ stats,
                                                   int n_rows)
{
    // sA (17408B) during GEMM; fH[64][FHLD] (33792B) + sB[64] (256B) for pool.
    __shared__ __align__(16) char smem[64 * FHLD * 4 + 256];
    unsigned short* sA = (unsigned short*)smem;

    int t = threadIdx.x;
    int wave = t >> 6, l = t & 63;
    int lr = l & 15;
    int lk = l >> 4;
    int row0 = blockIdx.x * 64;
    int col0 = wave * 32;

    // stage A tile: 64 rows x 128 bf16
    #pragma unroll
    for (int it = 0; it < 4; ++it) {
        int idx = it * 256 + t;          // 0..1023
        int r = idx >> 4, c8 = idx & 15;
        int gr = row0 + r;
        int4 vh = make_int4(0, 0, 0, 0);
        if (gr < n_rows) vh = ((const int4*)(A + (size_t)gr * 128))[c8];
        *(int4*)&sA[r * LDA + c8 * 8] = vh;
    }
    __syncthreads();

    f32x4 acc[4][2];
    #pragma unroll
    for (int m = 0; m < 4; ++m)
        #pragma unroll
        for (int n = 0; n < 2; ++n) acc[m][n] = (f32x4){0.f, 0.f, 0.f, 0.f};

    // ---- layer 1: acc = A @ W1 ----
    #pragma unroll
    for (int ks = 0; ks < 4; ++ks) {
        bf16x8 bfrag[2];
        #pragma unroll
        for (int n = 0; n < 2; ++n) {
            int c = col0 + n * 16 + lr;
            bfrag[n] = *(const bf16x8*)(Wt1 + (size_t)c * 128 + ks * 32 + lk * 8);
        }
        #pragma unroll
        for (int m = 0; m < 4; ++m) {
            bf16x8 ah = *(const bf16x8*)&sA[(m * 16 + lr) * LDA + ks * 32 + lk * 8];
            #pragma unroll
            for (int n = 0; n < 2; ++n)
                acc[m][n] = __builtin_amdgcn_mfma_f32_16x16x32_bf16(ah, bfrag[n], acc[m][n], 0, 0, 0);
        }
    }
    __syncthreads();

    // ---- T1 = relu(acc + b1) -> bf16 back into sA ----
    #pragma unroll
    for (int n = 0; n < 2; ++n) {
        int c = col0 + n * 16 + lr;
        float bb = b1[c];
        #pragma unroll
        for (int m = 0; m < 4; ++m) {
            #pragma unroll
            for (int i = 0; i < 4; ++i) {
                int r = m * 16 + lk * 4 + i;
                sA[r * LDA + c] = f2bf(fmaxf(acc[m][n][i] + bb, 0.f));
            }
        }
    }
    __syncthreads();

    #pragma unroll
    for (int m = 0; m < 4; ++m)
        #pragma unroll
        for (int n = 0; n < 2; ++n) acc[m][n] = (f32x4){0.f, 0.f, 0.f, 0.f};

    // ---- layer 2: acc = T1 @ W2 ----
    #pragma unroll
    for (int ks = 0; ks < 4; ++ks) {
        bf16x8 bfrag[2];
        #pragma unroll
        for (int n = 0; n < 2; ++n) {
            int c = col0 + n * 16 + lr;
            bfrag[n] = *(const bf16x8*)(Wt2 + (size_t)c * 128 + ks * 32 + lk * 8);
        }
        #pragma unroll
        for (int m = 0; m < 4; ++m) {
            bf16x8 ah = *(const bf16x8*)&sA[(m * 16 + lr) * LDA + ks * 32 + lk * 8];
            #pragma unroll
            for (int n = 0; n < 2; ++n)
                acc[m][n] = __builtin_amdgcn_mfma_f32_16x16x32_bf16(ah, bfrag[n], acc[m][n], 0, 0, 0);
        }
    }

    // ---- epilogue: v = relu(acc + b2); BN stats via direct atomics ----
    float bb0 = b2[col0 + lr];
    float bb1 = b2[col0 + 16 + lr];
    int c0 = col0 + lr, c1 = col0 + 16 + lr;
    float v0s[4][4], v1s[4][4];
    float ps[2] = {0.f, 0.f}, pq[2] = {0.f, 0.f};
    #pragma unroll
    for (int m = 0; m < 4; ++m) {
        #pragma unroll
        for (int i = 0; i < 4; ++i) {
            int gr = row0 + m * 16 + lk * 4 + i;
            float v0 = fmaxf(acc[m][0][i] + bb0, 0.f);
            float v1 = fmaxf(acc[m][1][i] + bb1, 0.f);
            if (gr >= n_rows) { v0 = 0.f; v1 = 0.f; }
            v0s[m][i] = v0; v1s[m][i] = v1;
            ps[0] += v0; pq[0] += v0 * v0;
            ps[1] += v1; pq[1] += v1 * v1;
        }
    }
    #pragma unroll
    for (int n = 0; n < 2; ++n) {
        ps[n] += __shfl_xor(ps[n], 16); ps[n] += __shfl_xor(ps[n], 32);
        pq[n] += __shfl_xor(pq[n], 16); pq[n] += __shfl_xor(pq[n], 32);
    }
    if (lk == 0) {
        unsafeAtomicAdd(&stats[c0],       ps[0]);
        unsafeAtomicAdd(&stats[c1],       ps[1]);
        unsafeAtomicAdd(&stats[128 + c0], pq[0]);
        unsafeAtomicAdd(&stats[128 + c1], pq[1]);
    }

    __syncthreads();   // sA dead -> re-use LDS for pool staging
    float (*fH)[FHLD] = (float (*)[FHLD])smem;
    int* sB = (int*)(smem + 64 * FHLD * sizeof(float));
    if (t < 64) sB[t] = (row0 + t < n_rows) ? batch[row0 + t] : -1;
    #pragma unroll
    for (int m = 0; m < 4; ++m) {
        #pragma unroll
        for (int i = 0; i < 4; ++i) {
            int r = m * 16 + lk * 4 + i;
            fH[r][c0] = v0s[m][i];
            fH[r][c1] = v1s[m][i];
        }
    }
    __syncthreads();

    // segmented pool: thread t -> column t&127, rows (t>>7)*32 .. +31
    {
        int c = t & 127;
        int rbeg = (t >> 7) * 32, rend = rbeg + 32;
        float a = 0.f;
        int bcur = sB[rbeg];
        for (int r = rbeg; r < rend; ++r) {
            int b = sB[r];
            if (b != bcur) {
                if (bcur >= 0) unsafeAtomicAdd(&g_raw[(size_t)bcur * 128 + c], a);
                a = 0.f; bcur = b;
            }
            a += fH[r][c];
        }
        if (bcur >= 0) unsafeAtomicAdd(&g_raw[(size_t)bcur * 128 + c], a);
    }
}

// -------- head: 4 graphs/block (amortize Wf1 reads); BN-finalize inline -----
__global__ __launch_bounds__(256) void k_head(const float* __restrict__ g_raw,
                                              const int* __restrict__ cnt,
                                              const float* __restrict__ stats,
                                              const float* __restrict__ gamma,
                                              const float* __restrict__ beta,
                                              const float* __restrict__ Wf1,
                                              const float* __restrict__ bf1,
                                              const float* __restrict__ Wf2,
                                              const float* __restrict__ bf2,
                                              float* __restrict__ out, int n_rows)
{
    __shared__ float sg[4][128];
    __shared__ float sh[4][256];
    int t = threadIdx.x;
    int G0 = blockIdx.x * 4;
    if (t < 128) {
        float inv_n = 1.0f / (float)n_rows;
        float mean = stats[t] * inv_n;
        float var = stats[128 + t] * inv_n - mean * mean;
        float inv = rsqrtf(var + BN_EPS);
        float scale = gamma[t] * inv;
        float shift = beta[t] - mean * scale;
        #pragma unroll
        for (int gi = 0; gi < 4; ++gi) {
            float c = (float)cnt[G0 + gi];
            sg[gi][t] = g_raw[(size_t)(G0 + gi) * 128 + t] * scale + c * shift;
        }
    }
    __syncthreads();
    float a0 = bf1[t], a1 = a0, a2 = a0, a3 = a0;
    #pragma unroll 8
    for (int k = 0; k < 128; ++k) {
        float w = Wf1[k * 256 + t];
        a0 = fmaf(sg[0][k], w, a0);
        a1 = fmaf(sg[1][k], w, a1);
        a2 = fmaf(sg[2][k], w, a2);
        a3 = fmaf(sg[3][k], w, a3);
    }
    sh[0][t] = fmaxf(a0, 0.f);
    sh[1][t] = fmaxf(a1, 0.f);
    sh[2][t] = fmaxf(a2, 0.f);
    sh[3][t] = fmaxf(a3, 0.f);
    __syncthreads();
    if (t < 192) {
        int o = t >> 4, l = t & 15;
        float p0 = 0.f, p1 = 0.f, p2 = 0.f, p3 = 0.f;
        for (int k = l; k < 256; k += 16) {
            float w = Wf2[k * 12 + o];
            p0 += sh[0][k] * w;
            p1 += sh[1][k] * w;
            p2 += sh[2][k] * w;
            p3 += sh[3][k] * w;
        }
        #pragma unroll
        for (int m = 8; m >= 1; m >>= 1) {
            p0 += __shfl_xor(p0, m, 16);
            p1 += __shfl_xor(p1, m, 16);
            p2 += __shfl_xor(p2, m, 16);
            p3 += __shfl_xor(p3, m, 16);
        }
        if (l == 0) {
            float bb = bf2[o];
            out[(size_t)(G0 + 0) * 12 + o] = p0 + bb;
            out[(size_t)(G0 + 1) * 12 + o] = p1 + bb;
            out[(size_t)(G0 + 2) * 12 + o] = p2 + bb;
            out[(size_t)(G0 + 3) * 12 + o] = p3 + bb;
        }
    }
}

extern "C" void kernel_launch(void* const* d_in, const int* in_sizes, int n_in,
                              void* d_out, int out_size, void* d_ws, size_t ws_size,
                              hipStream_t stream)
{
    const float* x     = (const float*)d_in[0];
    const int*   ei    = (const int*)d_in[1];
    const int*   batch = (const int*)d_in[2];
    const float* W1    = (const float*)d_in[3];
    const float* b1    = (const float*)d_in[4];
    const float* W2    = (const float*)d_in[5];
    const float* b2    = (const float*)d_in[6];
    const float* gamma = (const float*)d_in[7];
    const float* beta  = (const float*)d_in[8];
    const float* Wf1   = (const float*)d_in[9];
    const float* bf1   = (const float*)d_in[10];
    const float* Wf2   = (const float*)d_in[11];
    const float* bf2   = (const float*)d_in[12];

    int n_nodes = in_sizes[0] / N_FEAT;
    int n_edges = in_sizes[1] / 2;
    const int* src = ei;
    const int* dst = ei + n_edges;

    char* ws = (char*)d_ws;
    size_t planeBytes = (size_t)n_nodes * N_FEAT * sizeof(unsigned short);
    size_t gBytes     = (size_t)N_GRAPHS * N_FEAT * sizeof(float);
    int nblk_m = (n_nodes + 63) / 64;                 // mlp1 blocks
    int nb2    = (n_edges + EPB - 1) / EPB;           // partition blocks (<=256)
    int nbkt   = (n_nodes + 255) / 256;               // buckets (<=256)
    int nscan  = 256 * nb2;                           // bcnt/boff2 elements

    unsigned short* A   = (unsigned short*)ws;
    unsigned short* xb  = (unsigned short*)(ws + planeBytes);
    float* g_raw = (float*)(ws + 2 * planeBytes);
    float* stats = (float*)((char*)g_raw + gBytes);           // [256]
    float* scSp  = stats + 256;                               // [256] spare
    int*   cnt   = (int*)(scSp + 256);                        // [2048]
    int*   btot  = cnt + N_GRAPHS;                            // [256]
    unsigned short* Wt1 = (unsigned short*)(btot + 256);
    unsigned short* Wt2 = Wt1 + 128 * 128;
    char* p = (char*)(Wt2 + 128 * 128);
    int* row_start = (int*)p;   p += (size_t)(n_nodes + 1) * sizeof(int);
    int* bcnt      = (int*)p;   p += (size_t)nscan * sizeof(int);
    int* boff2     = (int*)p;   p += (size_t)nscan * sizeof(int);
    unsigned* epart = (unsigned*)p;  p += (size_t)n_edges * sizeof(unsigned);
    unsigned short* csr = (unsigned short*)p;  // [n_edges]

    // zero: g_raw + stats + spare + cnt + btot (contiguous)
    hipMemsetAsync(g_raw, 0,
                   gBytes + (256 + 256 + N_GRAPHS + 256) * sizeof(float), stream);

    // ---- fused prep (cvtx | cvtW | ghist | bhist) ----
    int n8 = n_nodes * N_FEAT / 8;
    int nbx = (n8 + 255) / 256;
    int nbg = (n_nodes + 255) / 256;
    k_prep<<<nbx + 128 + nbg + nb2, 256, 0, stream>>>(x, xb, n8, nbx, W1, W2, Wt1, Wt2,
                                                      batch, cnt, n_nodes, nbg,
                                                      dst, bcnt, btot, n_edges, nb2);

    // ---- CSR build via bucket sort (all stores LDS-staged + coalesced) ----
    k_bscan3<<<256, 256, 0, stream>>>(bcnt, btot, boff2, nb2);
    k_part<<<nb2, 256, 0, stream>>>(src, dst, boff2, epart, n_edges, nb2);
    k_bfill<<<nbkt, 256, 0, stream>>>(epart, boff2, row_start, csr, n_nodes, nb2, nbkt);

    // ---- pull aggregation (bf16 neighbors + bf16 self) -> bf16 A ----
    k_gather<<<(n_nodes + 3) / 4, 256, 0, stream>>>(xb, csr, row_start, A, n_nodes);

    // ---- MFMA MLP (+ BN stats atomics + segmented pool) ----
    k_mlp1_mfma<<<nblk_m, 256, 0, stream>>>(A, Wt1, b1, Wt2, b2, batch,
                                            g_raw, stats, n_nodes);

    // ---- head: 4 graphs/block, BN finalize inline ----
    k_head<<<N_GRAPHS / 4, 256, 0, stream>>>(g_raw, cnt, stats, gamma, beta,
                                             Wf1, bf1, Wf2, bf2, (float*)d_out, n_nodes);
}

// Round 17
// 121.998 us; speedup vs baseline: 1.0896x; 1.0896x over previous
//
#include <hip/hip_runtime.h>

#define N_FEAT   128
#define N_GRAPHS 2048
#define BN_EPS   1e-5f
#define LDA      136   // padded LDS row length (bf16 elems)
#define FHLD     132   // padded float row length for pool staging
#define EPB      4096  // edges per partition block (nb2 = ceil(E/EPB) <= 256 required)

typedef __attribute__((ext_vector_type(8))) short  bf16x8;
typedef __attribute__((ext_vector_type(4))) float  f32x4;

__device__ __forceinline__ unsigned short f2bf(float f) {
    union { float f; unsigned int u; } c; c.f = f;
    unsigned int r = c.u + 0x7fffu + ((c.u >> 16) & 1u);   // RNE
    return (unsigned short)(r >> 16);
}
__device__ __forceinline__ float bf2f(unsigned short h) {
    union { unsigned int u; float f; } c; c.u = ((unsigned int)h) << 16;
    return c.f;
}

// add 8 packed bf16 (int4) into acc[8]
__device__ __forceinline__ void acc8(float* a, int4 u) {
    unsigned int w[4] = {(unsigned int)u.x, (unsigned int)u.y,
                         (unsigned int)u.z, (unsigned int)u.w};
    #pragma unroll
    for (int k = 0; k < 4; ++k) {
        a[2 * k]     += __uint_as_float(w[k] << 16);
        a[2 * k + 1] += __uint_as_float(w[k] & 0xffff0000u);
    }
}

// -------- fused prep: x->bf16 | W transpose->bf16 | graph counts | bhist ----
__global__ __launch_bounds__(256) void k_prep(const float* __restrict__ x,
                                              unsigned short* __restrict__ xb,
                                              int n8, int nbx,
                                              const float* __restrict__ W1,
                                              const float* __restrict__ W2,
                                              unsigned short* __restrict__ Wt1,
                                              unsigned short* __restrict__ Wt2,
                                              const int* __restrict__ batch,
                                              int* __restrict__ cnt, int n_nodes,
                                              int nbg,
                                              const int* __restrict__ dst,
                                              int* __restrict__ bcnt,
                                              int* __restrict__ btot,
                                              int n_edges, int nb2)
{
    int b = blockIdx.x, t = threadIdx.x;
    if (b < nbx) {
        int i = b * 256 + t;
        if (i >= n8) return;
        float4 a = ((const float4*)x)[i * 2];
        float4 c = ((const float4*)x)[i * 2 + 1];
        ushort4 u0, u1;
        u0.x = f2bf(a.x); u0.y = f2bf(a.y); u0.z = f2bf(a.z); u0.w = f2bf(a.w);
        u1.x = f2bf(c.x); u1.y = f2bf(c.y); u1.z = f2bf(c.z); u1.w = f2bf(c.w);
        ((ushort4*)xb)[i * 2]     = u0;
        ((ushort4*)xb)[i * 2 + 1] = u1;
    } else if (b < nbx + 128) {
        int i = (b - nbx) * 256 + t;   // 0..32767
        int which = i >> 14;
        int k = (i >> 7) & 127;
        int c = i & 127;
        const float* W = which ? W2 : W1;
        unsigned short* O = which ? Wt2 : Wt1;
        O[c * 128 + k] = f2bf(W[k * 128 + c]);
    } else if (b < nbx + 128 + nbg) {
        int i = (b - nbx - 128) * 256 + t;
        if (i < n_nodes) atomicAdd(&cnt[batch[i]], 1);
    } else {
        // bhist section: per-(block,bucket) histogram of dst
        __shared__ int lc[256];
        int blk = b - nbx - 128 - nbg;   // 0..nb2-1
        lc[t] = 0;
        __syncthreads();
        int base = blk * EPB;
        for (int i = t; i < EPB; i += 256) {
            int e = base + i;
            if (e < n_edges) atomicAdd(&lc[dst[e] >> 8], 1);
        }
        __syncthreads();
        bcnt[t * nb2 + blk] = lc[t];
        if (lc[t]) atomicAdd(&btot[t], lc[t]);
    }
}

// ---------------- CSR scan in ONE kernel ------------------------------------
__global__ __launch_bounds__(256) void k_bscan3(const int* __restrict__ bcnt,
                                                const int* __restrict__ btot,
                                                int* __restrict__ boff2, int nb2)
{
    __shared__ int s[256];
    int t = threadIdx.x, b = blockIdx.x;
    s[t] = (t < b) ? btot[t] : 0;
    __syncthreads();
    for (int o = 128; o > 0; o >>= 1) {
        if (t < o) s[t] += s[t + o];
        __syncthreads();
    }
    int base = s[0];
    __syncthreads();
    int c = (t < nb2) ? bcnt[b * nb2 + t] : 0;
    s[t] = c;
    __syncthreads();
    for (int o = 1; o < 256; o <<= 1) {
        int u = (t >= o) ? s[t - o] : 0;
        __syncthreads();
        s[t] += u;
        __syncthreads();
    }
    if (t < nb2) boff2[b * nb2 + t] = base + s[t] - c;
}

// ---------------- CSR sort stage 2: partition edges by bucket ----------------
__global__ __launch_bounds__(256) void k_part(const int* __restrict__ src,
                                              const int* __restrict__ dst,
                                              const int* __restrict__ boff2,
                                              unsigned* __restrict__ epart,
                                              int n_edges, int nb2)
{
    __shared__ int lc[256];
    __shared__ int lofs[256];
    __shared__ unsigned buf[EPB];
    int t = threadIdx.x, blk = blockIdx.x;
    int base = blk * EPB;
    lc[t] = 0;
    __syncthreads();
    for (int i = t; i < EPB; i += 256) {
        int e = base + i;
        if (e < n_edges) atomicAdd(&lc[dst[e] >> 8], 1);
    }
    __syncthreads();
    int v = lc[t];
    lofs[t] = v;
    __syncthreads();
    for (int o = 1; o < 256; o <<= 1) {
        int u = (t >= o) ? lofs[t - o] : 0;
        __syncthreads();
        lofs[t] += u;
        __syncthreads();
    }
    int excl = lofs[t] - v;
    __syncthreads();
    lofs[t] = excl;
    lc[t] = 0;
    __syncthreads();
    for (int i = t; i < EPB; i += 256) {
        int e = base + i;
        if (e < n_edges) {
            int d = dst[e];
            int b = d >> 8;
            unsigned pack = ((unsigned)d << 16) | (unsigned)src[e];
            int r = atomicAdd(&lc[b], 1);
            buf[lofs[b] + r] = pack;
        }
    }
    __syncthreads();
    int total = min(EPB, n_edges - base);
    for (int i = t; i < total; i += 256) {
        unsigned pack = buf[i];
        int b = pack >> 24;              // dst>>8
        int gpos = boff2[b * nb2 + blk] + (i - lofs[b]);
        epart[gpos] = pack;
    }
}

// ---------------- CSR sort stage 3: per-bucket fill (writes row_start too) --
__global__ __launch_bounds__(256) void k_bfill(const unsigned* __restrict__ epart,
                                               const int* __restrict__ boff2,
                                               int* __restrict__ row_start,
                                               unsigned short* __restrict__ csr,
                                               int n_nodes, int nb2, int nbkt)
{
    __shared__ int cur[256];
    __shared__ int sc2[256];
    __shared__ unsigned short seg[8192];
    int t = threadIdx.x, b = blockIdx.x;
    int node0 = b * 256;
    int nodes = min(256, n_nodes - node0);
    int ebeg = boff2[(size_t)b * nb2];
    int eend = (b + 1 < nbkt) ? boff2[(size_t)(b + 1) * nb2] : boff2[(size_t)nbkt * nb2];

    cur[t] = 0;
    __syncthreads();
    for (int i = ebeg + t; i < eend; i += 256)
        atomicAdd(&cur[(epart[i] >> 16) - node0], 1);
    __syncthreads();
    int v = cur[t];
    sc2[t] = v;
    __syncthreads();
    for (int o = 1; o < 256; o <<= 1) {
        int u = (t >= o) ? sc2[t - o] : 0;
        __syncthreads();
        sc2[t] += u;
        __syncthreads();
    }
    int excl = sc2[t] - v;
    if (t < nodes) row_start[node0 + t] = ebeg + excl;
    if (b == nbkt - 1 && t == 0) row_start[n_nodes] = eend;
    __syncthreads();
    cur[t] = excl;
    __syncthreads();
    for (int i = ebeg + t; i < eend; i += 256) {
        unsigned pack = epart[i];
        int idx = (pack >> 16) - node0;
        int slot = atomicAdd(&cur[idx], 1);
        seg[slot] = (unsigned short)(pack & 0xffffu);
    }
    __syncthreads();
    int seglen = eend - ebeg;
    for (int i = t; i < seglen; i += 256) csr[ebeg + i] = seg[i];
}

// ---------------- pull aggregation (bf16 neighbors + bf16 self) -> bf16 A ---
__global__ __launch_bounds__(256) void k_gather(const unsigned short* __restrict__ xb,
                                                const unsigned short* __restrict__ csr,
                                                const int* __restrict__ row_start,
                                                unsigned short* __restrict__ A,
                                                int n_nodes)
{
    int node = blockIdx.x * 4 + (threadIdx.x >> 6);
    if (node >= n_nodes) return;
    int l = threadIdx.x & 63;
    int q = l >> 4;          // quarter id: edge stream offset
    int lq = l & 15;         // feature group lq*8 .. lq*8+7
    const int4* xb4 = (const int4*)xb;
    int beg = row_start[node], end = row_start[node + 1];
    float a[8];
    #pragma unroll
    for (int i = 0; i < 8; ++i) a[i] = 0.f;

    int j = beg + q;
    for (; j + 12 < end; j += 16) {        // 16 edges in flight per wave
        int s0 = csr[j], s1 = csr[j + 4], s2 = csr[j + 8], s3 = csr[j + 12];
        int4 u0 = xb4[(size_t)s0 * 16 + lq];
        int4 u1 = xb4[(size_t)s1 * 16 + lq];
        int4 u2 = xb4[(size_t)s2 * 16 + lq];
        int4 u3 = xb4[(size_t)s3 * 16 + lq];
        acc8(a, u0);
        acc8(a, u1);
        acc8(a, u2);
        acc8(a, u3);
    }
    for (; j < end; j += 4) {
        int4 u = xb4[(size_t)csr[j] * 16 + lq];
        acc8(a, u);
    }
    #pragma unroll
    for (int i = 0; i < 8; ++i) {
        a[i] += __shfl_xor(a[i], 16);
        a[i] += __shfl_xor(a[i], 32);
    }
    if (q == 0) {
        int4 uself = xb4[(size_t)node * 16 + lq];
        acc8(a, uself);
        unsigned int hw[4];
        #pragma unroll
        for (int i = 0; i < 4; ++i) {
            unsigned short h0 = f2bf(a[2 * i]);
            unsigned short h1 = f2bf(a[2 * i + 1]);
            hw[i] = (unsigned int)h0 | ((unsigned int)h1 << 16);
        }
        *(int4*)(A + (size_t)node * 128 + lq * 8) = make_int4(hw[0], hw[1], hw[2], hw[3]);
    }
}

// ---------------- fused MLP1 via MFMA + BN partials + segmented pool --------
__global__ __launch_bounds__(256) void k_mlp1_mfma(const unsigned short* __restrict__ A,
                                                   const unsigned short* __restrict__ Wt1,
                                                   const float* __restrict__ b1,
                                                   const unsigned short* __restrict__ Wt2,
                                                   const float* __restrict__ b2,
                                                   const int* __restrict__ batch,
                                                   float* __restrict__ g_raw,
                                                   float* __restrict__ partial,
                                                   int n_rows)
{
    // sA (17408B) during GEMM; fH[64][FHLD] (33792B) + sB[64] (256B) for pool.
    __shared__ __align__(16) char smem[64 * FHLD * 4 + 256];
    unsigned short* sA = (unsigned short*)smem;

    int t = threadIdx.x;
    int wave = t >> 6, l = t & 63;
    int lr = l & 15;
    int lk = l >> 4;
    int row0 = blockIdx.x * 64;
    int col0 = wave * 32;

    // stage A tile: 64 rows x 128 bf16
    #pragma unroll
    for (int it = 0; it < 4; ++it) {
        int idx = it * 256 + t;          // 0..1023
        int r = idx >> 4, c8 = idx & 15;
        int gr = row0 + r;
        int4 vh = make_int4(0, 0, 0, 0);
        if (gr < n_rows) vh = ((const int4*)(A + (size_t)gr * 128))[c8];
        *(int4*)&sA[r * LDA + c8 * 8] = vh;
    }
    __syncthreads();

    f32x4 acc[4][2];
    #pragma unroll
    for (int m = 0; m < 4; ++m)
        #pragma unroll
        for (int n = 0; n < 2; ++n) acc[m][n] = (f32x4){0.f, 0.f, 0.f, 0.f};

    // ---- layer 1: acc = A @ W1 ----
    #pragma unroll
    for (int ks = 0; ks < 4; ++ks) {
        bf16x8 bfrag[2];
        #pragma unroll
        for (int n = 0; n < 2; ++n) {
            int c = col0 + n * 16 + lr;
            bfrag[n] = *(const bf16x8*)(Wt1 + (size_t)c * 128 + ks * 32 + lk * 8);
        }
        #pragma unroll
        for (int m = 0; m < 4; ++m) {
            bf16x8 ah = *(const bf16x8*)&sA[(m * 16 + lr) * LDA + ks * 32 + lk * 8];
            #pragma unroll
            for (int n = 0; n < 2; ++n)
                acc[m][n] = __builtin_amdgcn_mfma_f32_16x16x32_bf16(ah, bfrag[n], acc[m][n], 0, 0, 0);
        }
    }
    __syncthreads();

    // ---- T1 = relu(acc + b1) -> bf16 back into sA ----
    #pragma unroll
    for (int n = 0; n < 2; ++n) {
        int c = col0 + n * 16 + lr;
        float bb = b1[c];
        #pragma unroll
        for (int m = 0; m < 4; ++m) {
            #pragma unroll
            for (int i = 0; i < 4; ++i) {
                int r = m * 16 + lk * 4 + i;
                sA[r * LDA + c] = f2bf(fmaxf(acc[m][n][i] + bb, 0.f));
            }
        }
    }
    __syncthreads();

    #pragma unroll
    for (int m = 0; m < 4; ++m)
        #pragma unroll
        for (int n = 0; n < 2; ++n) acc[m][n] = (f32x4){0.f, 0.f, 0.f, 0.f};

    // ---- layer 2: acc = T1 @ W2 ----
    #pragma unroll
    for (int ks = 0; ks < 4; ++ks) {
        bf16x8 bfrag[2];
        #pragma unroll
        for (int n = 0; n < 2; ++n) {
            int c = col0 + n * 16 + lr;
            bfrag[n] = *(const bf16x8*)(Wt2 + (size_t)c * 128 + ks * 32 + lk * 8);
        }
        #pragma unroll
        for (int m = 0; m < 4; ++m) {
            bf16x8 ah = *(const bf16x8*)&sA[(m * 16 + lr) * LDA + ks * 32 + lk * 8];
            #pragma unroll
            for (int n = 0; n < 2; ++n)
                acc[m][n] = __builtin_amdgcn_mfma_f32_16x16x32_bf16(ah, bfrag[n], acc[m][n], 0, 0, 0);
        }
    }

    // ---- epilogue: v = relu(acc + b2); BN partials ----
    float bb0 = b2[col0 + lr];
    float bb1 = b2[col0 + 16 + lr];
    int c0 = col0 + lr, c1 = col0 + 16 + lr;
    float v0s[4][4], v1s[4][4];
    float ps[2] = {0.f, 0.f}, pq[2] = {0.f, 0.f};
    #pragma unroll
    for (int m = 0; m < 4; ++m) {
        #pragma unroll
        for (int i = 0; i < 4; ++i) {
            int gr = row0 + m * 16 + lk * 4 + i;
            float v0 = fmaxf(acc[m][0][i] + bb0, 0.f);
            float v1 = fmaxf(acc[m][1][i] + bb1, 0.f);
            if (gr >= n_rows) { v0 = 0.f; v1 = 0.f; }
            v0s[m][i] = v0; v1s[m][i] = v1;
            ps[0] += v0; pq[0] += v0 * v0;
            ps[1] += v1; pq[1] += v1 * v1;
        }
    }
    #pragma unroll
    for (int n = 0; n < 2; ++n) {
        ps[n] += __shfl_xor(ps[n], 16); ps[n] += __shfl_xor(ps[n], 32);
        pq[n] += __shfl_xor(pq[n], 16); pq[n] += __shfl_xor(pq[n], 32);
    }
    if (lk == 0) {
        partial[(size_t)blockIdx.x * 256 + c0]       = ps[0];
        partial[(size_t)blockIdx.x * 256 + c1]       = ps[1];
        partial[(size_t)blockIdx.x * 256 + 128 + c0] = pq[0];
        partial[(size_t)blockIdx.x * 256 + 128 + c1] = pq[1];
    }

    __syncthreads();   // sA dead -> re-use LDS for pool staging
    float (*fH)[FHLD] = (float (*)[FHLD])smem;
    int* sB = (int*)(smem + 64 * FHLD * sizeof(float));
    if (t < 64) sB[t] = (row0 + t < n_rows) ? batch[row0 + t] : -1;
    #pragma unroll
    for (int m = 0; m < 4; ++m) {
        #pragma unroll
        for (int i = 0; i < 4; ++i) {
            int r = m * 16 + lk * 4 + i;
            fH[r][c0] = v0s[m][i];
            fH[r][c1] = v1s[m][i];
        }
    }
    __syncthreads();

    // segmented pool: thread t -> column t&127, rows (t>>7)*32 .. +31
    {
        int c = t & 127;
        int rbeg = (t >> 7) * 32, rend = rbeg + 32;
        float a = 0.f;
        int bcur = sB[rbeg];
        for (int r = rbeg; r < rend; ++r) {
            int b = sB[r];
            if (b != bcur) {
                if (bcur >= 0) unsafeAtomicAdd(&g_raw[(size_t)bcur * 128 + c], a);
                a = 0.f; bcur = b;
            }
            a += fH[r][c];
        }
        if (bcur >= 0) unsafeAtomicAdd(&g_raw[(size_t)bcur * 128 + c], a);
    }
}

// ---------------- reduce BN partials ----------------------------------------
__global__ __launch_bounds__(256) void k_bnred(const float* __restrict__ partial,
                                               float* __restrict__ stats, int nblk)
{
    int j = threadIdx.x;
    float s = 0.f;
    for (int b = blockIdx.x; b < nblk; b += gridDim.x)
        s += partial[(size_t)b * 256 + j];
    unsafeAtomicAdd(&stats[j], s);
}

// -------- head: 4 graphs/block (amortize Wf1 reads); BN-finalize inline -----
__global__ __launch_bounds__(256) void k_head(const float* __restrict__ g_raw,
                                              const int* __restrict__ cnt,
                                              const float* __restrict__ stats,
                                              const float* __restrict__ gamma,
                                              const float* __restrict__ beta,
                                              const float* __restrict__ Wf1,
                                              const float* __restrict__ bf1,
                                              const float* __restrict__ Wf2,
                                              const float* __restrict__ bf2,
                                              float* __restrict__ out, int n_rows)
{
    __shared__ float sg[4][128];
    __shared__ float sh[4][256];
    int t = threadIdx.x;
    int G0 = blockIdx.x * 4;
    if (t < 128) {
        float inv_n = 1.0f / (float)n_rows;
        float mean = stats[t] * inv_n;
        float var = stats[128 + t] * inv_n - mean * mean;
        float inv = rsqrtf(var + BN_EPS);
        float scale = gamma[t] * inv;
        float shift = beta[t] - mean * scale;
        #pragma unroll
        for (int gi = 0; gi < 4; ++gi) {
            float c = (float)cnt[G0 + gi];
            sg[gi][t] = g_raw[(size_t)(G0 + gi) * 128 + t] * scale + c * shift;
        }
    }
    __syncthreads();
    float a0 = bf1[t], a1 = a0, a2 = a0, a3 = a0;
    #pragma unroll 8
    for (int k = 0; k < 128; ++k) {
        float w = Wf1[k * 256 + t];
        a0 = fmaf(sg[0][k], w, a0);
        a1 = fmaf(sg[1][k], w, a1);
        a2 = fmaf(sg[2][k], w, a2);
        a3 = fmaf(sg[3][k], w, a3);
    }
    sh[0][t] = fmaxf(a0, 0.f);
    sh[1][t] = fmaxf(a1, 0.f);
    sh[2][t] = fmaxf(a2, 0.f);
    sh[3][t] = fmaxf(a3, 0.f);
    __syncthreads();
    if (t < 192) {
        int o = t >> 4, l = t & 15;
        float p0 = 0.f, p1 = 0.f, p2 = 0.f, p3 = 0.f;
        for (int k = l; k < 256; k += 16) {
            float w = Wf2[k * 12 + o];
            p0 += sh[0][k] * w;
            p1 += sh[1][k] * w;
            p2 += sh[2][k] * w;
            p3 += sh[3][k] * w;
        }
        #pragma unroll
        for (int m = 8; m >= 1; m >>= 1) {
            p0 += __shfl_xor(p0, m, 16);
            p1 += __shfl_xor(p1, m, 16);
            p2 += __shfl_xor(p2, m, 16);
            p3 += __shfl_xor(p3, m, 16);
        }
        if (l == 0) {
            float bb = bf2[o];
            out[(size_t)(G0 + 0) * 12 + o] = p0 + bb;
            out[(size_t)(G0 + 1) * 12 + o] = p1 + bb;
            out[(size_t)(G0 + 2) * 12 + o] = p2 + bb;
            out[(size_t)(G0 + 3) * 12 + o] = p3 + bb;
        }
    }
}

extern "C" void kernel_launch(void* const* d_in, const int* in_sizes, int n_in,
                              void* d_out, int out_size, void* d_ws, size_t ws_size,
                              hipStream_t stream)
{
    const float* x     = (const float*)d_in[0];
    const int*   ei    = (const int*)d_in[1];
    const int*   batch = (const int*)d_in[2];
    const float* W1    = (const float*)d_in[3];
    const float* b1    = (const float*)d_in[4];
    const float* W2    = (const float*)d_in[5];
    const float* b2    = (const float*)d_in[6];
    const float* gamma = (const float*)d_in[7];
    const float* beta  = (const float*)d_in[8];
    const float* Wf1   = (const float*)d_in[9];
    const float* bf1   = (const float*)d_in[10];
    const float* Wf2   = (const float*)d_in[11];
    const float* bf2   = (const float*)d_in[12];

    int n_nodes = in_sizes[0] / N_FEAT;
    int n_edges = in_sizes[1] / 2;
    const int* src = ei;
    const int* dst = ei + n_edges;

    char* ws = (char*)d_ws;
    size_t planeBytes = (size_t)n_nodes * N_FEAT * sizeof(unsigned short);
    size_t gBytes     = (size_t)N_GRAPHS * N_FEAT * sizeof(float);
    int nblk_m = (n_nodes + 63) / 64;                 // mlp1 blocks
    int nb2    = (n_edges + EPB - 1) / EPB;           // partition blocks (<=256)
    int nbkt   = (n_nodes + 255) / 256;               // buckets (<=256)
    int nscan  = 256 * nb2;                           // bcnt/boff2 elements

    unsigned short* A   = (unsigned short*)ws;
    unsigned short* xb  = (unsigned short*)(ws + planeBytes);
    float* g_raw = (float*)(ws + 2 * planeBytes);
    float* stats = (float*)((char*)g_raw + gBytes);           // [256]
    float* scSp  = stats + 256;                               // [256] spare
    int*   cnt   = (int*)(scSp + 256);                        // [2048]
    int*   btot  = cnt + N_GRAPHS;                            // [256]
    unsigned short* Wt1 = (unsigned short*)(btot + 256);
    unsigned short* Wt2 = Wt1 + 128 * 128;
    float* partial = (float*)(Wt2 + 128 * 128);               // [nblk_m][256]
    char* p = (char*)(partial + (size_t)nblk_m * 256);
    int* row_start = (int*)p;   p += (size_t)(n_nodes + 1) * sizeof(int);
    int* bcnt      = (int*)p;   p += (size_t)nscan * sizeof(int);
    int* boff2     = (int*)p;   p += (size_t)nscan * sizeof(int);
    unsigned* epart = (unsigned*)p;  p += (size_t)n_edges * sizeof(unsigned);
    unsigned short* csr = (unsigned short*)p;  // [n_edges]

    // zero: g_raw + stats + spare + cnt + btot (contiguous)
    hipMemsetAsync(g_raw, 0,
                   gBytes + (256 + 256 + N_GRAPHS + 256) * sizeof(float), stream);

    // ---- fused prep (cvtx | cvtW | ghist | bhist) ----
    int n8 = n_nodes * N_FEAT / 8;
    int nbx = (n8 + 255) / 256;
    int nbg = (n_nodes + 255) / 256;
    k_prep<<<nbx + 128 + nbg + nb2, 256, 0, stream>>>(x, xb, n8, nbx, W1, W2, Wt1, Wt2,
                                                      batch, cnt, n_nodes, nbg,
                                                      dst, bcnt, btot, n_edges, nb2);

    // ---- CSR build via bucket sort (all stores LDS-staged + coalesced) ----
    k_bscan3<<<256, 256, 0, stream>>>(bcnt, btot, boff2, nb2);
    k_part<<<nb2, 256, 0, stream>>>(src, dst, boff2, epart, n_edges, nb2);
    k_bfill<<<nbkt, 256, 0, stream>>>(epart, boff2, row_start, csr, n_nodes, nb2, nbkt);

    // ---- pull aggregation (bf16 neighbors + bf16 self) -> bf16 A ----
    k_gather<<<(n_nodes + 3) / 4, 256, 0, stream>>>(xb, csr, row_start, A, n_nodes);

    // ---- MFMA MLP (+ BN partials + segmented pool) ----
    k_mlp1_mfma<<<nblk_m, 256, 0, stream>>>(A, Wt1, b1, Wt2, b2, batch,
                                            g_raw, partial, n_nodes);

    // ---- BN reduce + head (4 graphs/block, BN finalize inline) ----
    k_bnred<<<64, 256, 0, stream>>>(partial, stats, nblk_m);
    k_head<<<N_GRAPHS / 4, 256, 0, stream>>>(g_raw, cnt, stats, gamma, beta,
                                             Wf1, bf1, Wf2, bf2, (float*)d_out, n_nodes);
}